// Round 4
// baseline (492.765 us; speedup 1.0000x reference)
//
#include <hip/hip_runtime.h>

// LinearGaussianSystem via Woodbury:
//   M  = R + H Pinv H^T                (16x16, per batch)
//   Sigma = Pinv - (Pinv H^T) M^-1 (H Pinv) = Pinv - G^T W,  W = M^-1 G, G = H Pinv
//   mu = mu0 + G^T M^-1 (y - c) = mu0 + W^T (y - c)   [uses Pinv symmetric => Gt = G^T]
// Setup kernel precomputes batch-constant factors into d_ws:
//   ws[0..255]     Acm[j][i]  = A[i][j],  A = (H Pinv) H^T   (column-major)
//   ws[256..767]   gcm[s][o]  = G[o][s]                       (G columns as rows)
//   ws[768..1279]  gtc[o][s]  = Gt[s][o], Gt = Pinv H^T       (Gt columns as rows)
//   ws[1792..2815] pvt[c][r]  = Pinv[r][c]                    (Pinv transposed)
//   ws[2816..2831] cvec[o]    = bias[o] + (H mu0)[o]
//   ws[2832..2863] mu0[s]

__global__ void lgs_setup(const float* __restrict__ H, const float* __restrict__ bias,
                          const float* __restrict__ mu0, const float* __restrict__ P,
                          float* __restrict__ ws)
{
    __shared__ float aug[32][65];   // [P | I] augmented, padded stride 65
    __shared__ float colk[32];
    __shared__ float Gs[16][32];    // G = H Pinv
    __shared__ float Gts[32][16];   // Gt = Pinv H^T
    const int tid = threadIdx.x;    // 64 threads

    for (int idx = tid; idx < 32 * 64; idx += 64) {
        int r = idx >> 6, c = idx & 63;
        aug[r][c] = (c < 32) ? P[r * 32 + c] : (((c - 32) == r) ? 1.0f : 0.0f);
    }
    __syncthreads();

    // Gauss-Jordan inversion of P (SPD -> no pivoting). Thread tid owns column tid.
    for (int k = 0; k < 32; ++k) {
        if (tid < 32) colk[tid] = aug[tid][k];
        __syncthreads();
        float rk = aug[k][tid] * (1.0f / colk[k]);
        aug[k][tid] = rk;
        for (int r = 0; r < 32; ++r)
            if (r != k) aug[r][tid] -= colk[r] * rk;
        __syncthreads();
    }
    // Pinv[r][c] = aug[r][32+c]

    for (int idx = tid; idx < 16 * 32; idx += 64) {
        int o = idx >> 5, s = idx & 31;
        float acc = 0.f;
        for (int u = 0; u < 32; ++u) acc += H[o * 32 + u] * aug[u][32 + s];
        Gs[o][s] = acc;
    }
    for (int idx = tid; idx < 32 * 16; idx += 64) {
        int s = idx >> 4, o = idx & 15;
        float acc = 0.f;
        for (int u = 0; u < 32; ++u) acc += aug[s][32 + u] * H[o * 32 + u];
        Gts[s][o] = acc;
    }
    __syncthreads();

    for (int idx = tid; idx < 256; idx += 64) {       // Acm[j][i] = A[i][j]
        int j = idx >> 4, i = idx & 15;
        float acc = 0.f;
        for (int s = 0; s < 32; ++s) acc += Gs[i][s] * H[j * 32 + s];
        ws[idx] = acc;
    }
    for (int idx = tid; idx < 512; idx += 64) {       // gcm[s][o] = G[o][s]
        int s = idx >> 4, o = idx & 15;
        ws[256 + idx] = Gs[o][s];
    }
    for (int idx = tid; idx < 512; idx += 64) {       // gtc[o][s] = Gt[s][o]
        int o = idx >> 5, s = idx & 31;
        ws[768 + idx] = Gts[s][o];
    }
    for (int idx = tid; idx < 1024; idx += 64) {      // pvt[c][r] = Pinv[r][c]
        int c = idx >> 5, r = idx & 31;
        ws[1792 + idx] = aug[r][32 + c];
    }
    if (tid < 16) {
        float acc = bias[tid];
        for (int s = 0; s < 32; ++s) acc += H[tid * 32 + s] * mu0[s];
        ws[2816 + tid] = acc;
    }
    if (tid < 32) ws[2832 + tid] = mu0[tid];
}

// Broadcast x from lane K of each 32-lane half: BitMode offset = (xor<<10)|(or<<5)|and,
// here and=0, or=K -> src = K (half-local). Two batches per wave, one per half.
#define BCAST32(x, K) __int_as_float(__builtin_amdgcn_ds_swizzle(__float_as_int(x), ((K) << 5)))

// Column-wise GJ solve step. Lane u owns M-column (u&15) in m[] and RHS column u in w[].
// After 16 steps, w = W[:,u] = (M^-1 G)[:,u].
template <int K>
__device__ __forceinline__ void gj32(int u, float (&m)[16], float (&w)[16])
{
    if (u == K) m[K] = 1.0f / m[K];   // column owner publishes inv-pivot in slot K
    float bc[16];
#pragma unroll
    for (int i = 0; i < 16; ++i) bc[i] = BCAST32(m[i], K);
    // bc[K] = 1/pivot, bc[i!=K] = pivot-column entry m[i][K]
    float pk = m[K] * bc[K];          // meaningful for columns u>K; dead elsewhere
#pragma unroll
    for (int i = 0; i < 16; ++i)
        if (i != K) m[i] -= bc[i] * pk;
    m[K] = pk;
    float a = w[K] * bc[K];
#pragma unroll
    for (int i = 0; i < 16; ++i)
        if (i != K) w[i] -= bc[i] * a;
    w[K] = a;
}

__global__ __launch_bounds__(256, 4) void lgs_main(
    const float* __restrict__ obs, const float* __restrict__ noise,
    const float* __restrict__ ws,
    float* __restrict__ out_mean, float* __restrict__ out_cov, int B)
{
    const int u = threadIdx.x & 31;                        // Sigma/W column owner
    const int t = u & 15;                                  // M column owner
    const int half = threadIdx.x >> 5;                     // 8 batch slots per block

    const float* __restrict__ Acm  = ws;            // [16][16]
    const float* __restrict__ gcm  = ws + 256;      // [32][16]
    const float* __restrict__ gtc  = ws + 768;      // [16][32]
    const float* __restrict__ pvt  = ws + 1792;     // [32][32]
    const float* __restrict__ cvec = ws + 2816;     // [16]
    const float* __restrict__ m0v  = ws + 2832;     // [32]

    const int stride = gridDim.x * 8;

    // Grid-stride over batch groups: few large blocks instead of 8192 tiny ones
    // (command-processor dispatch rate was the round-3 occupancy cap).
    for (int b = blockIdx.x * 8 + half; b < B; b += stride) {
        float m[16], w[16];

        // M column t = R column t + A column t (R symmetric -> read row t, contiguous).
        const float4* Rr = (const float4*)(noise + (size_t)b * 256 + t * 16);
        const float4* Ar = (const float4*)(Acm + t * 16);
#pragma unroll
        for (int i = 0; i < 4; ++i) {
            float4 r = Rr[i], a = Ar[i];
            m[4*i+0] = r.x + a.x; m[4*i+1] = r.y + a.y;
            m[4*i+2] = r.z + a.z; m[4*i+3] = r.w + a.w;
        }
        // RHS column u: w = G[:,u]
        const float4* G4 = (const float4*)(gcm + u * 16);
#pragma unroll
        for (int i = 0; i < 4; ++i) {
            float4 g = G4[i];
            w[4*i+0] = g.x; w[4*i+1] = g.y; w[4*i+2] = g.z; w[4*i+3] = g.w;
        }

        gj32<0>(u, m, w);   gj32<1>(u, m, w);   gj32<2>(u, m, w);   gj32<3>(u, m, w);
        gj32<4>(u, m, w);   gj32<5>(u, m, w);   gj32<6>(u, m, w);   gj32<7>(u, m, w);
        gj32<8>(u, m, w);   gj32<9>(u, m, w);   gj32<10>(u, m, w);  gj32<11>(u, m, w);
        gj32<12>(u, m, w);  gj32<13>(u, m, w);  gj32<14>(u, m, w);  gj32<15>(u, m, w);

        // posterior mean, fully local: mu[u] = mu0[u] + sum_o W[o][u] * (y - c)[o]
        {
            float mu = m0v[u];
            const float4* Y4 = (const float4*)(obs + (size_t)b * 16);
            const float4* C4 = (const float4*)cvec;
#pragma unroll
            for (int i = 0; i < 4; ++i) {
                float4 y = Y4[i], c = C4[i];
                mu += w[4*i+0] * (y.x - c.x);
                mu += w[4*i+1] * (y.y - c.y);
                mu += w[4*i+2] * (y.z - c.z);
                mu += w[4*i+3] * (y.w - c.w);
            }
            out_mean[(size_t)b * 32 + u] = mu;   // 32 lanes contiguous
        }

        // Sigma column u (= row u by symmetry), 2 chunks of 16 rows:
        //   acc[s] = Pinv[s][u] - sum_o Gt[s][o] * W[o][u]
        float* Crow = out_cov + (size_t)b * 1024 + u * 32;
#pragma unroll
        for (int c = 0; c < 2; ++c) {
            float acc[16];
            const float4* P4 = (const float4*)(pvt + u * 32 + c * 16);
#pragma unroll
            for (int i = 0; i < 4; ++i) {
                float4 p = P4[i];
                acc[4*i+0] = p.x; acc[4*i+1] = p.y; acc[4*i+2] = p.z; acc[4*i+3] = p.w;
            }
#pragma unroll
            for (int o = 0; o < 16; ++o) {
                const float4* g4 = (const float4*)(gtc + o * 32 + c * 16);
                float f = w[o];
#pragma unroll
                for (int i = 0; i < 4; ++i) {
                    float4 g = g4[i];
                    acc[4*i+0] -= g.x * f;
                    acc[4*i+1] -= g.y * f;
                    acc[4*i+2] -= g.z * f;
                    acc[4*i+3] -= g.w * f;
                }
            }
            float4* Cs = (float4*)(Crow + c * 16);
#pragma unroll
            for (int i = 0; i < 4; ++i)
                Cs[i] = make_float4(acc[4*i+0], acc[4*i+1], acc[4*i+2], acc[4*i+3]);
        }
    }
}

extern "C" void kernel_launch(void* const* d_in, const int* in_sizes, int n_in,
                              void* d_out, int out_size, void* d_ws, size_t ws_size,
                              hipStream_t stream)
{
    const float* obs   = (const float*)d_in[0];   // [B,16]
    const float* noise = (const float*)d_in[1];   // [B,16,16]
    const float* H     = (const float*)d_in[2];   // [16,32]
    const float* bias  = (const float*)d_in[3];   // [16]
    const float* mu0   = (const float*)d_in[4];   // [32]
    const float* P     = (const float*)d_in[5];   // [32,32]
    float* ws = (float*)d_ws;

    const int B = in_sizes[0] / 16;
    float* out_mean = (float*)d_out;
    float* out_cov  = out_mean + (size_t)B * 32;

    int nblocks = (B + 7) / 8;
    if (nblocks > 2048) nblocks = 2048;   // 8 blocks/CU, grid-stride the rest

    lgs_setup<<<1, 64, 0, stream>>>(H, bias, mu0, P, ws);
    lgs_main<<<nblocks, 256, 0, stream>>>(obs, noise, ws, out_mean, out_cov, B);
}

// Round 5
// 183.106 us; speedup vs baseline: 2.6911x; 2.6911x over previous
//
#include <hip/hip_runtime.h>

// LinearGaussianSystem via Woodbury:
//   M  = R + H Pinv H^T                (16x16, per batch)
//   Sigma = Pinv - (Pinv H^T) M^-1 (H Pinv) = Pinv - G^T W,  W = M^-1 G, G = H Pinv
//   mu = mu0 + G^T M^-1 (y - c) = mu0 + W^T (y - c)   [uses Pinv symmetric => Gt = G^T]
// Setup kernel precomputes batch-constant factors into d_ws:
//   ws[0..255]     Acm[j][i]  = A[i][j],  A = (H Pinv) H^T   (column-major)
//   ws[256..767]   gcm[s][o]  = G[o][s]                       (G columns as rows)
//   ws[768..1279]  gtc[o][s]  = Gt[s][o], Gt = Pinv H^T       (Gt columns as rows)
//   ws[1792..2815] pvt[c][r]  = Pinv[r][c]                    (Pinv transposed)
//   ws[2816..2831] cvec[o]    = bias[o] + (H mu0)[o]
//   ws[2832..2863] mu0[s]

__global__ void lgs_setup(const float* __restrict__ H, const float* __restrict__ bias,
                          const float* __restrict__ mu0, const float* __restrict__ P,
                          float* __restrict__ ws)
{
    __shared__ float aug[32][65];   // [P | I] augmented, padded stride 65
    __shared__ float colk[32];
    __shared__ float Gs[16][32];    // G = H Pinv
    __shared__ float Gts[32][16];   // Gt = Pinv H^T
    const int tid = threadIdx.x;    // 64 threads

    for (int idx = tid; idx < 32 * 64; idx += 64) {
        int r = idx >> 6, c = idx & 63;
        aug[r][c] = (c < 32) ? P[r * 32 + c] : (((c - 32) == r) ? 1.0f : 0.0f);
    }
    __syncthreads();

    // Gauss-Jordan inversion of P (SPD -> no pivoting). Thread tid owns column tid.
    for (int k = 0; k < 32; ++k) {
        if (tid < 32) colk[tid] = aug[tid][k];
        __syncthreads();
        float rk = aug[k][tid] * (1.0f / colk[k]);
        aug[k][tid] = rk;
        for (int r = 0; r < 32; ++r)
            if (r != k) aug[r][tid] -= colk[r] * rk;
        __syncthreads();
    }
    // Pinv[r][c] = aug[r][32+c]

    for (int idx = tid; idx < 16 * 32; idx += 64) {
        int o = idx >> 5, s = idx & 31;
        float acc = 0.f;
        for (int u = 0; u < 32; ++u) acc += H[o * 32 + u] * aug[u][32 + s];
        Gs[o][s] = acc;
    }
    for (int idx = tid; idx < 32 * 16; idx += 64) {
        int s = idx >> 4, o = idx & 15;
        float acc = 0.f;
        for (int u = 0; u < 32; ++u) acc += aug[s][32 + u] * H[o * 32 + u];
        Gts[s][o] = acc;
    }
    __syncthreads();

    for (int idx = tid; idx < 256; idx += 64) {       // Acm[j][i] = A[i][j]
        int j = idx >> 4, i = idx & 15;
        float acc = 0.f;
        for (int s = 0; s < 32; ++s) acc += Gs[i][s] * H[j * 32 + s];
        ws[idx] = acc;
    }
    for (int idx = tid; idx < 512; idx += 64) {       // gcm[s][o] = G[o][s]
        int s = idx >> 4, o = idx & 15;
        ws[256 + idx] = Gs[o][s];
    }
    for (int idx = tid; idx < 512; idx += 64) {       // gtc[o][s] = Gt[s][o]
        int o = idx >> 5, s = idx & 31;
        ws[768 + idx] = Gts[s][o];
    }
    for (int idx = tid; idx < 1024; idx += 64) {      // pvt[c][r] = Pinv[r][c]
        int c = idx >> 5, r = idx & 31;
        ws[1792 + idx] = aug[r][32 + c];
    }
    if (tid < 16) {
        float acc = bias[tid];
        for (int s = 0; s < 32; ++s) acc += H[tid * 32 + s] * mu0[s];
        ws[2816 + tid] = acc;
    }
    if (tid < 32) ws[2832 + tid] = mu0[tid];
}

// Broadcast x from lane K of each 32-lane half: BitMode offset = (xor<<10)|(or<<5)|and,
// here and=0, or=K -> src = K (half-local). Two batches per wave, one per half.
#define BCAST32(x, K) __int_as_float(__builtin_amdgcn_ds_swizzle(__float_as_int(x), ((K) << 5)))

// Column-wise GJ solve step. Lane u owns M-column (u&15) in m[] and RHS column u in w[].
// After 16 steps, w = W[:,u] = (M^-1 G)[:,u].
template <int K>
__device__ __forceinline__ void gj32(int u, float (&m)[16], float (&w)[16])
{
    if (u == K) m[K] = 1.0f / m[K];   // column owner publishes inv-pivot in slot K
    float bc[16];
#pragma unroll
    for (int i = 0; i < 16; ++i) bc[i] = BCAST32(m[i], K);
    // bc[K] = 1/pivot, bc[i!=K] = pivot-column entry m[i][K]
    float pk = m[K] * bc[K];          // meaningful for columns u>K; dead elsewhere
#pragma unroll
    for (int i = 0; i < 16; ++i)
        if (i != K) m[i] -= bc[i] * pk;
    m[K] = pk;
    float a = w[K] * bc[K];
#pragma unroll
    for (int i = 0; i < 16; ++i)
        if (i != K) w[i] -= bc[i] * a;
    w[K] = a;
}

__global__ __launch_bounds__(1024, 4) void lgs_main(
    const float* __restrict__ obs, const float* __restrict__ noise,
    const float* __restrict__ ws,
    float* __restrict__ out_mean, float* __restrict__ out_cov, int B)
{
    const int u = threadIdx.x & 31;                        // Sigma/W column owner
    const int t = u & 15;                                  // M column owner
    const int b = blockIdx.x * 32 + (threadIdx.x >> 5);    // 32 batches per 1024-thr block
    if (b >= B) return;

    const float* __restrict__ Acm  = ws;            // [16][16]
    const float* __restrict__ gcm  = ws + 256;      // [32][16]
    const float* __restrict__ gtc  = ws + 768;      // [16][32]
    const float* __restrict__ pvt  = ws + 1792;     // [32][32]
    const float* __restrict__ cvec = ws + 2816;     // [16]
    const float* __restrict__ m0v  = ws + 2832;     // [32]

    float m[16], w[16];

    // M column t = R column t + A column t (R symmetric -> read row t, contiguous).
    const float4* Rr = (const float4*)(noise + (size_t)b * 256 + t * 16);
    const float4* Ar = (const float4*)(Acm + t * 16);
#pragma unroll
    for (int i = 0; i < 4; ++i) {
        float4 r = Rr[i], a = Ar[i];
        m[4*i+0] = r.x + a.x; m[4*i+1] = r.y + a.y;
        m[4*i+2] = r.z + a.z; m[4*i+3] = r.w + a.w;
    }
    // RHS column u: w = G[:,u]
    const float4* G4 = (const float4*)(gcm + u * 16);
#pragma unroll
    for (int i = 0; i < 4; ++i) {
        float4 g = G4[i];
        w[4*i+0] = g.x; w[4*i+1] = g.y; w[4*i+2] = g.z; w[4*i+3] = g.w;
    }

    gj32<0>(u, m, w);   gj32<1>(u, m, w);   gj32<2>(u, m, w);   gj32<3>(u, m, w);
    gj32<4>(u, m, w);   gj32<5>(u, m, w);   gj32<6>(u, m, w);   gj32<7>(u, m, w);
    gj32<8>(u, m, w);   gj32<9>(u, m, w);   gj32<10>(u, m, w);  gj32<11>(u, m, w);
    gj32<12>(u, m, w);  gj32<13>(u, m, w);  gj32<14>(u, m, w);  gj32<15>(u, m, w);

    // posterior mean, fully local: mu[u] = mu0[u] + sum_o W[o][u] * (y - c)[o]
    {
        float mu = m0v[u];
        const float4* Y4 = (const float4*)(obs + (size_t)b * 16);
        const float4* C4 = (const float4*)cvec;
#pragma unroll
        for (int i = 0; i < 4; ++i) {
            float4 y = Y4[i], c = C4[i];
            mu += w[4*i+0] * (y.x - c.x);
            mu += w[4*i+1] * (y.y - c.y);
            mu += w[4*i+2] * (y.z - c.z);
            mu += w[4*i+3] * (y.w - c.w);
        }
        out_mean[(size_t)b * 32 + u] = mu;   // 32 lanes contiguous
    }

    // Sigma column u (= row u by symmetry), 2 chunks of 16 rows:
    //   acc[s] = Pinv[s][u] - sum_o Gt[s][o] * W[o][u]
    float* Crow = out_cov + (size_t)b * 1024 + u * 32;
#pragma unroll
    for (int c = 0; c < 2; ++c) {
        float acc[16];
        const float4* P4 = (const float4*)(pvt + u * 32 + c * 16);
#pragma unroll
        for (int i = 0; i < 4; ++i) {
            float4 p = P4[i];
            acc[4*i+0] = p.x; acc[4*i+1] = p.y; acc[4*i+2] = p.z; acc[4*i+3] = p.w;
        }
#pragma unroll
        for (int o = 0; o < 16; ++o) {
            const float4* g4 = (const float4*)(gtc + o * 32 + c * 16);
            float f = w[o];
#pragma unroll
            for (int i = 0; i < 4; ++i) {
                float4 g = g4[i];
                acc[4*i+0] -= g.x * f;
                acc[4*i+1] -= g.y * f;
                acc[4*i+2] -= g.z * f;
                acc[4*i+3] -= g.w * f;
            }
        }
        float4* Cs = (float4*)(Crow + c * 16);
#pragma unroll
        for (int i = 0; i < 4; ++i)
            Cs[i] = make_float4(acc[4*i+0], acc[4*i+1], acc[4*i+2], acc[4*i+3]);
    }
}

extern "C" void kernel_launch(void* const* d_in, const int* in_sizes, int n_in,
                              void* d_out, int out_size, void* d_ws, size_t ws_size,
                              hipStream_t stream)
{
    const float* obs   = (const float*)d_in[0];   // [B,16]
    const float* noise = (const float*)d_in[1];   // [B,16,16]
    const float* H     = (const float*)d_in[2];   // [16,32]
    const float* bias  = (const float*)d_in[3];   // [16]
    const float* mu0   = (const float*)d_in[4];   // [32]
    const float* P     = (const float*)d_in[5];   // [32,32]
    float* ws = (float*)d_ws;

    const int B = in_sizes[0] / 16;
    float* out_mean = (float*)d_out;
    float* out_cov  = out_mean + (size_t)B * 32;

    lgs_setup<<<1, 64, 0, stream>>>(H, bias, mu0, P, ws);
    lgs_main<<<(B + 31) / 32, 1024, 0, stream>>>(obs, noise, ws, out_mean, out_cov, B);
}

// Round 6
// 142.000 us; speedup vs baseline: 3.4702x; 1.2895x over previous
//
#include <hip/hip_runtime.h>
#include <hip/hip_bf16.h>

// LinearGaussianSystem via Woodbury:
//   M  = R + H Pinv H^T                (16x16, per batch)
//   Sigma = Pinv - G^T W,  W = M^-1 G, G = H Pinv   (Pinv symmetric => Gt = G^T)
//   mu = mu0 + W^T (y - c),  c = bias + H mu0
// Sigma epilogue runs on MFMA (bf16): D = A*B + C with
//   A = -0.5 * Gt  (K=16 duplicated into k=16..31, so no zero-padding needed)
//   B = W, k-duplicated the same way;  C = Pinv fragment  => D = Pinv - Gt*W.
// Robustness: Gt*M^-1*G is symmetric (transpose-convention-proof) and A/B frags
// share one (lane,elem)->k map (k-permutation-proof).
//
// ws layout (floats):
//   0    : Acm[16][16]  A=(H Pinv)H^T column-major
//   256  : gcm[32][16]  G columns as rows
//   768  : af[2][64][4] A-frags, packed bf16 pairs (uint), tile r=0,1
//   1280 : pf[4][64][4] Pinv D-layout frags, tile t=(r*2+c)
//   2816 : cvec[16]     bias + H mu0
//   2832 : m0v[32]      mu0

typedef __attribute__((ext_vector_type(8))) short bf16x8;
typedef __attribute__((ext_vector_type(4))) float f32x4;

__device__ __forceinline__ unsigned bf16rne(float f) {
    unsigned x = __float_as_uint(f);
    return (x + 0x7FFFu + ((x >> 16) & 1u)) >> 16;
}

__global__ void lgs_setup(const float* __restrict__ H, const float* __restrict__ bias,
                          const float* __restrict__ mu0, const float* __restrict__ P,
                          float* __restrict__ ws)
{
    __shared__ float aug[32][65];   // [P | I] augmented, padded stride 65
    __shared__ float colk[32];
    __shared__ float Gs[16][32];    // G = H Pinv
    __shared__ float Gts[32][16];   // Gt = Pinv H^T
    const int tid = threadIdx.x;    // 256 threads

    for (int idx = tid; idx < 2048; idx += 256) {
        int r = idx >> 6, c = idx & 63;
        aug[r][c] = (c < 32) ? P[r * 32 + c] : (((c - 32) == r) ? 1.0f : 0.0f);
    }
    __syncthreads();

    // Gauss-Jordan inversion of P (SPD -> no pivoting). Thread tid<64 owns column tid.
    for (int k = 0; k < 32; ++k) {
        if (tid < 32) colk[tid] = aug[tid][k];
        __syncthreads();
        if (tid < 64) {
            float rk = aug[k][tid] * (1.0f / colk[k]);
            aug[k][tid] = rk;
            for (int r = 0; r < 32; ++r)
                if (r != k) aug[r][tid] -= colk[r] * rk;
        }
        __syncthreads();
    }
    // Pinv[r][c] = aug[r][32+c]

    for (int idx = tid; idx < 512; idx += 256) {
        int o = idx >> 5, s = idx & 31;
        float acc = 0.f;
        for (int v = 0; v < 32; ++v) acc += H[o * 32 + v] * aug[v][32 + s];
        Gs[o][s] = acc;
    }
    for (int idx = tid; idx < 512; idx += 256) {
        int s = idx >> 4, o = idx & 15;
        float acc = 0.f;
        for (int v = 0; v < 32; ++v) acc += aug[s][32 + v] * H[o * 32 + v];
        Gts[s][o] = acc;
    }
    __syncthreads();

    for (int idx = tid; idx < 256; idx += 256) {      // Acm[j][i] = A[i][j]
        int j = idx >> 4, i = idx & 15;
        float acc = 0.f;
        for (int s = 0; s < 32; ++s) acc += Gs[i][s] * H[j * 32 + s];
        ws[idx] = acc;
    }
    for (int idx = tid; idx < 512; idx += 256) {      // gcm[s][o] = G[o][s]
        int s = idx >> 4, o = idx & 15;
        ws[256 + idx] = Gs[o][s];
    }
    // A-frags: af[r][l][j] = pack(-0.5*Gt[16r+(l&15)][kb], -0.5*Gt[...][kb+1])
    // with kb = ((l>>4)*8 + 2j) & 15  (k duplicated across halves)
    {
        unsigned* wsu = (unsigned*)ws;
        for (int idx = tid; idx < 512; idx += 256) {
            int r = idx >> 8, rem = idx & 255;
            int l = rem >> 2, j = rem & 3;
            int mm = 16 * r + (l & 15);
            int kb = (((l >> 4) * 8) + 2 * j) & 15;
            float v0 = -0.5f * Gts[mm][kb];
            float v1 = -0.5f * Gts[mm][kb + 1];
            wsu[768 + idx] = bf16rne(v0) | (bf16rne(v1) << 16);
        }
    }
    // Pinv frags in MFMA C/D layout: pf[t][l][j] = Pinv[16*(t>>1)+((l>>4)*4)+j][16*(t&1)+(l&15)]
    for (int idx = tid; idx < 1024; idx += 256) {
        int tt = idx >> 8, rem = idx & 255;
        int l = rem >> 2, j = rem & 3;
        int row = 16 * (tt >> 1) + ((l >> 4) << 2) + j;
        int col = 16 * (tt & 1) + (l & 15);
        ws[1280 + idx] = aug[row][32 + col];
    }
    if (tid < 16) {
        float acc = bias[tid];
        for (int s = 0; s < 32; ++s) acc += H[tid * 32 + s] * mu0[s];
        ws[2816 + tid] = acc;
    }
    if (tid < 32) ws[2832 + tid] = mu0[tid];
}

// Broadcast x from lane K of each 32-lane half (BitMode offset: and=0, or=K).
#define BCAST32(x, K) __int_as_float(__builtin_amdgcn_ds_swizzle(__float_as_int(x), ((K) << 5)))

// Column-wise GJ solve step. Lane u owns M-column (u&15) in m[] and RHS column u in w[].
template <int K>
__device__ __forceinline__ void gj32(int u, float (&m)[16], float (&w)[16])
{
    if (u == K) m[K] = 1.0f / m[K];   // column owner publishes inv-pivot in slot K
    float bc[16];
#pragma unroll
    for (int i = 0; i < 16; ++i) bc[i] = BCAST32(m[i], K);
    float pk = m[K] * bc[K];          // meaningful for columns u>K; dead elsewhere
#pragma unroll
    for (int i = 0; i < 16; ++i)
        if (i != K) m[i] -= bc[i] * pk;
    m[K] = pk;
    float a = w[K] * bc[K];
#pragma unroll
    for (int i = 0; i < 16; ++i)
        if (i != K) w[i] -= bc[i] * a;
    w[K] = a;
}

__global__ __launch_bounds__(1024, 4) void lgs_main(
    const float* __restrict__ obs, const float* __restrict__ noise,
    const float* __restrict__ ws,
    float* __restrict__ out_mean, float* __restrict__ out_cov, int B)
{
    // Wave-private W staging: [32 slots][32 cols][16 k], XOR-swizzled k. 64 KB.
    __shared__ float ld[16384];

    const int tid  = threadIdx.x;
    const int l    = tid & 63;                       // lane
    const int u    = tid & 31;                       // W/Sigma column owner
    const int t    = u & 15;                         // M column owner
    const int slot = tid >> 5;                       // batch slot in block (0..31)
    const int wv   = tid >> 6;                       // wave in block
    const int b    = blockIdx.x * 32 + slot;
    const int bb   = (b < B) ? b : (B - 1);          // clamp (keeps waves full)

    const float* __restrict__ Acm  = ws;             // [16][16]
    const float* __restrict__ gcm  = ws + 256;       // [32][16]
    const float* __restrict__ cvec = ws + 2816;      // [16]
    const float* __restrict__ m0v  = ws + 2832;      // [32]

    float m[16], w[16];

    // M column t = R column t + A column t (R symmetric -> read row t, contiguous).
    const float4* Rr = (const float4*)(noise + (size_t)bb * 256 + t * 16);
    const float4* Ar = (const float4*)(Acm + t * 16);
#pragma unroll
    for (int i = 0; i < 4; ++i) {
        float4 r = Rr[i], a = Ar[i];
        m[4*i+0] = r.x + a.x; m[4*i+1] = r.y + a.y;
        m[4*i+2] = r.z + a.z; m[4*i+3] = r.w + a.w;
    }
    // RHS column u: w = G[:,u]
    const float4* G4 = (const float4*)(gcm + u * 16);
#pragma unroll
    for (int i = 0; i < 4; ++i) {
        float4 g = G4[i];
        w[4*i+0] = g.x; w[4*i+1] = g.y; w[4*i+2] = g.z; w[4*i+3] = g.w;
    }

    gj32<0>(u, m, w);   gj32<1>(u, m, w);   gj32<2>(u, m, w);   gj32<3>(u, m, w);
    gj32<4>(u, m, w);   gj32<5>(u, m, w);   gj32<6>(u, m, w);   gj32<7>(u, m, w);
    gj32<8>(u, m, w);   gj32<9>(u, m, w);   gj32<10>(u, m, w);  gj32<11>(u, m, w);
    gj32<12>(u, m, w);  gj32<13>(u, m, w);  gj32<14>(u, m, w);  gj32<15>(u, m, w);

    // posterior mean, fully local: mu[u] = mu0[u] + sum_o W[o][u] * (y - c)[o]
    {
        float mu = m0v[u];
        const float4* Y4 = (const float4*)(obs + (size_t)bb * 16);
        const float4* C4 = (const float4*)cvec;
#pragma unroll
        for (int i = 0; i < 4; ++i) {
            float4 y = Y4[i], c = C4[i];
            mu += w[4*i+0] * (y.x - c.x);
            mu += w[4*i+1] * (y.y - c.y);
            mu += w[4*i+2] * (y.z - c.z);
            mu += w[4*i+3] * (y.w - c.w);
        }
        if (b < B) out_mean[(size_t)b * 32 + u] = mu;
    }

    // Stage W into LDS (wave-private slice; same-wave DS is in-order -> no barrier).
    // k' = k ^ ((col&3)<<2) keeps b128 blocks contiguous and spreads banks.
    {
        const int xw = (u & 3) << 2;
        float* wb = &ld[slot * 512 + u * 16];
        *(float4*)&wb[ 0 ^ xw] = make_float4(w[0],  w[1],  w[2],  w[3]);
        *(float4*)&wb[ 4 ^ xw] = make_float4(w[4],  w[5],  w[6],  w[7]);
        *(float4*)&wb[ 8 ^ xw] = make_float4(w[8],  w[9],  w[10], w[11]);
        *(float4*)&wb[12 ^ xw] = make_float4(w[12], w[13], w[14], w[15]);
    }

    // Constant frags (lane-indexed, L1-hot)
    const uint4*  AF4 = (const uint4*) (ws + 768);
    const float4* PF4 = (const float4*)(ws + 1280);
    uint4 a0u = AF4[l], a1u = AF4[64 + l];
    bf16x8 A0, A1;
    __builtin_memcpy(&A0, &a0u, 16);
    __builtin_memcpy(&A1, &a1u, 16);
    f32x4 pfr[4];
#pragma unroll
    for (int tt = 0; tt < 4; ++tt) {
        float4 p = PF4[tt * 64 + l];
        pfr[tt][0] = p.x; pfr[tt][1] = p.y; pfr[tt][2] = p.z; pfr[tt][3] = p.w;
    }

    const int k0 = ((l >> 4) * 8) & 15;   // k-dup: groups 2,3 re-read 0..15
    const int xr = (l & 3) << 2;
#pragma unroll
    for (int h = 0; h < 2; ++h) {
        const int bh = blockIdx.x * 32 + wv * 2 + h;
        const int rbase = (wv * 2 + h) * 512 + (l & 15) * 16;
#pragma unroll
        for (int c = 0; c < 2; ++c) {
            const float* rb = &ld[rbase + c * 256];
            float4 f0 = *(const float4*)&rb[(k0    ) ^ xr];
            float4 f1 = *(const float4*)&rb[(k0 + 4) ^ xr];
            __hip_bfloat162 q0 = __float22bfloat162_rn(make_float2(f0.x, f0.y));
            __hip_bfloat162 q1 = __float22bfloat162_rn(make_float2(f0.z, f0.w));
            __hip_bfloat162 q2 = __float22bfloat162_rn(make_float2(f1.x, f1.y));
            __hip_bfloat162 q3 = __float22bfloat162_rn(make_float2(f1.z, f1.w));
            unsigned bu[4];
            __builtin_memcpy(&bu[0], &q0, 4);
            __builtin_memcpy(&bu[1], &q1, 4);
            __builtin_memcpy(&bu[2], &q2, 4);
            __builtin_memcpy(&bu[3], &q3, 4);
            bf16x8 Bf;
            __builtin_memcpy(&Bf, bu, 16);
#pragma unroll
            for (int r = 0; r < 2; ++r) {
                f32x4 d = __builtin_amdgcn_mfma_f32_16x16x32_bf16(
                    r ? A1 : A0, Bf, pfr[r * 2 + c], 0, 0, 0);
                if (bh < B) {
                    float* S = out_cov + (size_t)bh * 1024
                             + (16 * r + ((l >> 4) << 2)) * 32 + 16 * c + (l & 15);
                    S[0]  = d[0];
                    S[32] = d[1];
                    S[64] = d[2];
                    S[96] = d[3];
                }
            }
        }
    }
}

extern "C" void kernel_launch(void* const* d_in, const int* in_sizes, int n_in,
                              void* d_out, int out_size, void* d_ws, size_t ws_size,
                              hipStream_t stream)
{
    const float* obs   = (const float*)d_in[0];   // [B,16]
    const float* noise = (const float*)d_in[1];   // [B,16,16]
    const float* H     = (const float*)d_in[2];   // [16,32]
    const float* bias  = (const float*)d_in[3];   // [16]
    const float* mu0   = (const float*)d_in[4];   // [32]
    const float* P     = (const float*)d_in[5];   // [32,32]
    float* ws = (float*)d_ws;

    const int B = in_sizes[0] / 16;
    float* out_mean = (float*)d_out;
    float* out_cov  = out_mean + (size_t)B * 32;

    lgs_setup<<<1, 256, 0, stream>>>(H, bias, mu0, P, ws);
    lgs_main<<<(B + 31) / 32, 1024, 0, stream>>>(obs, noise, ws, out_mean, out_cov, B);
}